// Round 1
// baseline (349.081 us; speedup 1.0000x reference)
//
#include <hip/hip_runtime.h>

// SparseLinear: out[b, j] = sum_{e: dst[e]==j} values[e] * x[b, src[e]] + bias[j]
// Inputs (setup_inputs order):
//   d_in[0] = x       float32 (B, N_IN, 1)
//   d_in[1] = values  float32 (NNZ,)
//   d_in[2] = bias    float32 (N_OUT, 1)
//   d_in[3] = indices int32   (2, NNZ)  row0=src, row1=dst
//   d_in[4] = n_out   int32   scalar
// Output: float32 (B, N_OUT, 1)

// ---------- transpose x (B, N) -> xT (N, B), B == 32 ----------
__global__ void xpose_in_kernel(const float* __restrict__ x, float* __restrict__ xT, int N) {
    __shared__ float tile[32][33];
    int n0 = blockIdx.x * 32;
    int tx = threadIdx.x;  // 0..31
    int ty = threadIdx.y;  // 0..31
    // load: x[b=ty][n0+tx], coalesced along tx
    if (n0 + tx < N) tile[ty][tx] = x[ty * (long)N + n0 + tx];
    __syncthreads();
    // store: xT[(n0+ty)*32 + b=tx], coalesced along tx
    if (n0 + ty < N) xT[(long)(n0 + ty) * 32 + tx] = tile[tx][ty];
}

// ---------- edge scatter: accT[dst*32 + b] += v * xT[src*32 + b] ----------
__global__ void edge_kernel(const float* __restrict__ xT, const float* __restrict__ values,
                            const int* __restrict__ src, const int* __restrict__ dst,
                            float* __restrict__ accT, int nnz) {
    int tid = blockIdx.x * blockDim.x + threadIdx.x;
    int lane_b = tid & 31;       // batch index 0..31
    int e0 = tid >> 5;           // edge task
    int estride = (gridDim.x * blockDim.x) >> 5;
    for (int e = e0; e < nnz; e += estride) {
        int s = src[e];
        int d = dst[e];
        float v = values[e];
        float xv = xT[(long)s * 32 + lane_b];
        atomicAdd(&accT[(long)d * 32 + lane_b], v * xv);
    }
}

// ---------- epilogue: out[b*N + j] = accT[j*32 + b] + bias[j] ----------
__global__ void xpose_out_kernel(const float* __restrict__ accT, const float* __restrict__ bias,
                                 float* __restrict__ out, int N) {
    __shared__ float tile[32][33];
    int j0 = blockIdx.x * 32;
    int tx = threadIdx.x;  // 0..31
    int ty = threadIdx.y;  // 0..31
    // load accT[(j0+ty)*32 + b=tx], coalesced along tx
    if (j0 + ty < N) tile[ty][tx] = accT[(long)(j0 + ty) * 32 + tx];
    __syncthreads();
    // store out[b=ty][j0+tx], coalesced along tx
    if (j0 + tx < N) out[ty * (long)N + j0 + tx] = tile[tx][ty] + bias[j0 + tx];
}

// ---------- fallback (no workspace): direct strided atomics into out ----------
__global__ void edge_direct_kernel(const float* __restrict__ x, const float* __restrict__ values,
                                   const int* __restrict__ src, const int* __restrict__ dst,
                                   float* __restrict__ out, int nnz, int N_IN, int N_OUT) {
    int tid = blockIdx.x * blockDim.x + threadIdx.x;
    int lane_b = tid & 31;
    int e0 = tid >> 5;
    int estride = (gridDim.x * blockDim.x) >> 5;
    for (int e = e0; e < nnz; e += estride) {
        int s = src[e];
        int d = dst[e];
        float v = values[e];
        float xv = x[(long)lane_b * N_IN + s];
        atomicAdd(&out[(long)lane_b * N_OUT + d], v * xv);
    }
}

__global__ void init_out_bias_kernel(float* __restrict__ out, const float* __restrict__ bias,
                                     int N_OUT, int B) {
    long i = (long)blockIdx.x * blockDim.x + threadIdx.x;
    long total = (long)N_OUT * B;
    if (i < total) out[i] = bias[i % N_OUT];
}

extern "C" void kernel_launch(void* const* d_in, const int* in_sizes, int n_in,
                              void* d_out, int out_size, void* d_ws, size_t ws_size,
                              hipStream_t stream) {
    const float* x      = (const float*)d_in[0];
    const float* values = (const float*)d_in[1];
    const float* bias   = (const float*)d_in[2];
    const int*   idx    = (const int*)d_in[3];

    const int NNZ   = in_sizes[1];
    const int N_OUT = in_sizes[2];
    const int B     = out_size / N_OUT;         // 32
    const int N_IN  = in_sizes[0] / B;

    const int* src = idx;
    const int* dst = idx + NNZ;

    float* out = (float*)d_out;

    const size_t xT_bytes  = (size_t)N_IN * B * sizeof(float);
    const size_t acc_bytes = (size_t)N_OUT * B * sizeof(float);

    if (B == 32 && ws_size >= xT_bytes + acc_bytes) {
        float* xT   = (float*)d_ws;
        float* accT = (float*)((char*)d_ws + xT_bytes);

        // 1) transpose x -> xT (N_IN, 32)
        {
            dim3 blk(32, 32);
            dim3 grd((N_IN + 31) / 32);
            xpose_in_kernel<<<grd, blk, 0, stream>>>(x, xT, N_IN);
        }
        // 2) zero accumulator
        hipMemsetAsync(accT, 0, acc_bytes, stream);
        // 3) edge scatter
        {
            int threads = 256;
            int blocks = 4096;  // grid-stride, ~2 edges per wave per iter
            edge_kernel<<<blocks, threads, 0, stream>>>(xT, values, src, dst, accT, NNZ);
        }
        // 4) transpose + bias -> out
        {
            dim3 blk(32, 32);
            dim3 grd((N_OUT + 31) / 32);
            xpose_out_kernel<<<grd, blk, 0, stream>>>(accT, bias, out, N_OUT);
        }
    } else {
        // Fallback: correct but slower (strided atomics into out)
        {
            long total = (long)N_OUT * B;
            int threads = 256;
            long blocks = (total + threads - 1) / threads;
            init_out_bias_kernel<<<(int)blocks, threads, 0, stream>>>(out, bias, N_OUT, B);
        }
        {
            int threads = 256;
            int blocks = 4096;
            edge_direct_kernel<<<blocks, threads, 0, stream>>>(x, values, src, dst, out, NNZ, N_IN, N_OUT);
        }
    }
}